// Round 5
// baseline (2982.328 us; speedup 1.0000x reference)
//
#include <hip/hip_runtime.h>
#include <stdint.h>

#define B_    256
#define T_    1024
#define H_    512
#define NIN_  64
#define NOUT_ 64

// rnn_scan: 64 blocks x 4 waves (1 wave/SIMD -> 512-reg budget).
// Wave owns 128 cols (jt 0..7). W residency per wave:
//   kb 0..6  : AGPR  (7 kb x 8 jt = 56 units = 224 AGPRs, asm MFMA "a" operand)
//   kb 7..11 : VGPR  (5 kb x 8 jt = 40 units = 160 arch VGPRs, builtin MFMA)
//   kb 12..15: LDS   (4 kb x 512 cols = 128 KB, per-lane-linear, builtin MFMA)
#define SC_NW    4
#define BBLK     4
#define HROW     528     // hbuf row stride in shorts (1056B -> 8-bank shift/row)
#define KB_AG    7
#define KB_VG    5       // kb 7..11
#define KB_LDS   4       // kb 12..15
#define LDS_U    (KB_LDS * 8)   // 32 units per wave

typedef __attribute__((ext_vector_type(8))) short bf16x8;
typedef __attribute__((ext_vector_type(4))) float f32x4;

__device__ __forceinline__ short f2bf(float f) {
  uint32_t u = __float_as_uint(f);
  uint32_t r = (u + 0x7FFFu + ((u >> 16) & 1u)) >> 16;
  return (short)(r & 0xFFFFu);
}

__device__ __forceinline__ bf16x8 pack8(float4 lo, float4 hi) {
  bf16x8 s;
  s[0] = f2bf(lo.x); s[1] = f2bf(lo.y); s[2] = f2bf(lo.z); s[3] = f2bf(lo.w);
  s[4] = f2bf(hi.x); s[5] = f2bf(hi.y); s[6] = f2bf(hi.z); s[7] = f2bf(hi.w);
  return s;
}

__device__ __forceinline__ float fast_tanh(float x) {
  float e = __expf(2.0f * x);
  return 1.0f - __fdividef(2.0f, e + 1.0f);
}

// MFMA with B pinned in AGPR (forces AReg_128 class on b's live range)
__device__ __forceinline__ void mfma_agpr(f32x4& d, bf16x8 a, const bf16x8& b) {
  asm("v_mfma_f32_16x16x32_bf16 %0, %1, %2, %0" : "+v"(d) : "v"(a), "a"(b));
}

// ---------------------------------------------------------------------------
// xproj: inp[b,t,h] = X[b,t,:] @ Win[h,:]  (f32, written into hid region)
// ---------------------------------------------------------------------------
#define XP_BLOCKS 512
__global__ __launch_bounds__(512, 2) void xproj(
    const float* __restrict__ X, const float* __restrict__ Win,
    float* __restrict__ inp)
{
  const int tid  = threadIdx.x;
  const int lane = tid & 63;
  const int w    = tid >> 6;
  const int g    = lane >> 4;
  const int m    = lane & 15;

  bf16x8 Bf[2][4];
#pragma unroll
  for (int kb = 0; kb < 2; ++kb)
#pragma unroll
    for (int jt = 0; jt < 4; ++jt) {
      const int j = 64 * w + 16 * jt + m;
      const float4* p = reinterpret_cast<const float4*>(Win + (size_t)j * NIN_ + 32 * kb + 8 * g);
      Bf[kb][jt] = pack8(p[0], p[1]);
    }

  const int NTILES = (B_ * T_) / 16;
  const f32x4 zero = {0.f, 0.f, 0.f, 0.f};

  for (int tile = blockIdx.x; tile < NTILES; tile += XP_BLOCKS) {
    const size_t row0 = (size_t)tile * 16;
    f32x4 acc[4];
    {
      const float4* p = reinterpret_cast<const float4*>(X + (row0 + m) * NIN_ + 8 * g);
      const bf16x8 a = pack8(p[0], p[1]);
#pragma unroll
      for (int jt = 0; jt < 4; ++jt)
        acc[jt] = __builtin_amdgcn_mfma_f32_16x16x32_bf16(a, Bf[0][jt], zero, 0, 0, 0);
    }
    {
      const float4* p = reinterpret_cast<const float4*>(X + (row0 + m) * NIN_ + 32 + 8 * g);
      const bf16x8 a = pack8(p[0], p[1]);
#pragma unroll
      for (int jt = 0; jt < 4; ++jt)
        acc[jt] = __builtin_amdgcn_mfma_f32_16x16x32_bf16(a, Bf[1][jt], acc[jt], 0, 0, 0);
    }
#pragma unroll
    for (int jt = 0; jt < 4; ++jt)
#pragma unroll
      for (int r = 0; r < 4; ++r)
        inp[(row0 + 4 * g + r) * H_ + 64 * w + 16 * jt + m] = acc[jt][r];
  }
}

// ---------------------------------------------------------------------------
// rnn_scan
// ---------------------------------------------------------------------------
__global__ __launch_bounds__(SC_NW * 64, 1) void rnn_scan(
    const float* __restrict__ h0, const float* __restrict__ W,
    float* __restrict__ hid)
{
  __shared__ __align__(16) short wlds[SC_NW * LDS_U * 64 * 8];  // 128 KB: kb 12..15
  __shared__ __align__(16) short hbuf[2][BBLK][HROW];           // 8.25 KB

  const int tid  = threadIdx.x;
  const int lane = tid & 63;
  const int w    = tid >> 6;    // wave 0..3
  const int g    = lane >> 4;
  const int m    = lane & 15;
  const int b0   = blockIdx.x * BBLK;

  // --- AGPR-resident W: kb 0..6 (B[k][col] = W[col][k])
  bf16x8 Wa[KB_AG][8];
#pragma unroll
  for (int kb = 0; kb < KB_AG; ++kb)
#pragma unroll
    for (int jt = 0; jt < 8; ++jt) {
      const int col = 128 * w + 16 * jt + m;
      const float4* p = reinterpret_cast<const float4*>(W + (size_t)col * H_ + 32 * kb + 8 * g);
      Wa[kb][jt] = pack8(p[0], p[1]);
    }

  // --- VGPR-resident W: kb 7..11
  bf16x8 Wv[KB_VG][8];
#pragma unroll
  for (int k2 = 0; k2 < KB_VG; ++k2)
#pragma unroll
    for (int jt = 0; jt < 8; ++jt) {
      const int col = 128 * w + 16 * jt + m;
      const float4* p = reinterpret_cast<const float4*>(W + (size_t)col * H_ + 32 * (KB_AG + k2) + 8 * g);
      Wv[k2][jt] = pack8(p[0], p[1]);
    }

  // --- LDS-resident W: kb 12..15; unit u = (kb-12)*8 + jt per wave ww
  // layout: wlds[((ww*LDS_U + u)*64 + l)*8 .. +8) -> conflict-free linear b128
#pragma unroll
  for (int i = 0; i < 32; ++i) {
    const int c  = tid + 256 * i;           // < 8192 chunks of 8 shorts
    const int l  = c & 63;
    const int u  = (c >> 6) % LDS_U;
    const int ww = (c >> 6) / LDS_U;
    const int jt = u & 7;
    const int kb = 12 + (u >> 3);
    const int col = 128 * ww + 16 * jt + (l & 15);
    const int k0  = 32 * kb + (l >> 4) * 8;
    const float4* p = reinterpret_cast<const float4*>(W + (size_t)col * H_ + k0);
    *reinterpret_cast<bf16x8*>(&wlds[((size_t)(ww * LDS_U + u) * 64 + l) * 8]) = pack8(p[0], p[1]);
  }

  // --- hbuf[0] = tanh(h0)
  for (int e = tid; e < BBLK * H_; e += SC_NW * 64) {
    const int r = e >> 9, k = e & (H_ - 1);
    hbuf[0][r][k] = f2bf(fast_tanh(h0[(size_t)(b0 + r) * H_ + k]));
  }

  // --- inp_cur for t=0: lane owns cols 128w+16(g+4p)+m, p=0,1; rows 0..3
  float inp_cur[2][4];
#pragma unroll
  for (int p = 0; p < 2; ++p) {
    const int col = 128 * w + 16 * (g + 4 * p) + m;
#pragma unroll
    for (int r = 0; r < 4; ++r)
      inp_cur[p][r] = hid[((size_t)(b0 + r) * T_ + 0) * H_ + col];
  }

  __syncthreads();

  const int arow = m & 3;

#pragma clang loop unroll(disable)
  for (int t = 0; t < T_; ++t) {
    const int cur = t & 1, nxt = cur ^ 1;
    const short* hr = &hbuf[cur][arow][0];

    // inp prefetch for t+1 (global loads issued first, consumed in epilogue)
    float inp_nxt[2][4] = {{0.f,0.f,0.f,0.f},{0.f,0.f,0.f,0.f}};
    if (t + 1 < T_) {
#pragma unroll
      for (int p = 0; p < 2; ++p) {
        const int col = 128 * w + 16 * (g + 4 * p) + m;
#pragma unroll
        for (int r = 0; r < 4; ++r)
          inp_nxt[p][r] = hid[((size_t)(b0 + r) * T_ + (t + 1)) * H_ + col];
      }
    }

    f32x4 acc[8];
#pragma unroll
    for (int jt = 0; jt < 8; ++jt) acc[jt] = (f32x4){0.f, 0.f, 0.f, 0.f};
    asm volatile("s_nop 1" :::);   // VALU acc-init -> asm MFMA C-read hazard guard

    // Phase A: AGPR kbs 0..6 (inline asm, B from AGPR)
#pragma unroll
    for (int kb = 0; kb < KB_AG; ++kb) {
      const bf16x8 a = *reinterpret_cast<const bf16x8*>(hr + 32 * kb + 8 * g);
#pragma unroll
      for (int jt = 0; jt < 8; ++jt)
        mfma_agpr(acc[jt], a, Wa[kb][jt]);
    }

    // Phase L: LDS kbs 12..15 (builtin)
#pragma unroll
    for (int k2 = 0; k2 < KB_LDS; ++k2) {
      const int kb = 12 + k2;
      const bf16x8 a = *reinterpret_cast<const bf16x8*>(hr + 32 * kb + 8 * g);
#pragma unroll
      for (int jt = 0; jt < 8; ++jt) {
        const bf16x8 b = *reinterpret_cast<const bf16x8*>(
            &wlds[((size_t)(w * LDS_U + k2 * 8 + jt) * 64 + lane) * 8]);
        acc[jt] = __builtin_amdgcn_mfma_f32_16x16x32_bf16(a, b, acc[jt], 0, 0, 0);
      }
    }

    // Phase V: VGPR kbs 7..11 (builtin; last writer of acc is compiler-known)
#pragma unroll
    for (int k2 = 0; k2 < KB_VG; ++k2) {
      const bf16x8 a = *reinterpret_cast<const bf16x8*>(hr + 32 * (KB_AG + k2) + 8 * g);
#pragma unroll
      for (int jt = 0; jt < 8; ++jt)
        acc[jt] = __builtin_amdgcn_mfma_f32_16x16x32_bf16(a, Wv[k2][jt], acc[jt], 0, 0, 0);
    }

    // Epilogue: lane owns cols 128w+16(g+4p)+m; D row 4g+r -> batch row r
#pragma unroll
    for (int p = 0; p < 2; ++p) {
      const int col = 128 * w + 16 * (g + 4 * p) + m;
#pragma unroll
      for (int r = 0; r < 4; ++r) {
        float v = acc[4 * p + 0][r];
        v = (g == 1) ? acc[4 * p + 1][r] : v;
        v = (g == 2) ? acc[4 * p + 2][r] : v;
        v = (g == 3) ? acc[4 * p + 3][r] : v;
        v += inp_cur[p][r];
        hid[((size_t)(b0 + r) * T_ + t) * H_ + col] = v;
        hbuf[nxt][r][col] = f2bf(fast_tanh(v));
      }
    }
#pragma unroll
    for (int p = 0; p < 2; ++p)
#pragma unroll
      for (int r = 0; r < 4; ++r) inp_cur[p][r] = inp_nxt[p][r];

    // drain LDS ops only; vmcnt stays in flight (hid stores, inp loads)
    asm volatile("s_waitcnt lgkmcnt(0)" ::: "memory");
    __builtin_amdgcn_s_barrier();
    asm volatile("" ::: "memory");
  }
}

// ---------------------------------------------------------------------------
// out = hidden @ W_out^T : memory-bound [BT,512]x[512,64] MFMA GEMM.
// ---------------------------------------------------------------------------
#define OP_BLOCKS 1024
#define OP_WAVES  8
__global__ __launch_bounds__(OP_WAVES * 64, 2) void out_proj(
    const float* __restrict__ hid, const float* __restrict__ Wout,
    float* __restrict__ out)
{
  __shared__ __align__(16) short ws[16][NOUT_][32];   // 64 KB

  const int tid  = threadIdx.x;
  const int lane = tid & 63;
  const int w    = tid >> 6;
  const int g    = lane >> 4;
  const int m    = lane & 15;

#pragma unroll
  for (int i = 0; i < 8; ++i) {
    const int c   = tid + OP_WAVES * 64 * i;
    const int kb  = c >> 8;
    const int col = (c >> 2) & 63;
    const int q   = (c & 3) * 8;
    const float4* p = reinterpret_cast<const float4*>(Wout + (size_t)col * H_ + 32 * kb + q);
    *reinterpret_cast<bf16x8*>(&ws[kb][col][q]) = pack8(p[0], p[1]);
  }
  __syncthreads();

  const int wave_id = blockIdx.x * OP_WAVES + w;
  const int NWAVES  = OP_BLOCKS * OP_WAVES;
  const int NTILES  = (B_ * T_) / 16;

  for (int tile = wave_id; tile < NTILES; tile += NWAVES) {
    const size_t row0 = (size_t)tile * 16;
    f32x4 acc[4];
    {
      const float4* p = reinterpret_cast<const float4*>(hid + (row0 + m) * H_ + 8 * g);
      const bf16x8 a = pack8(p[0], p[1]);
      const f32x4 zero = {0.f, 0.f, 0.f, 0.f};
#pragma unroll
      for (int jt = 0; jt < 4; ++jt) {
        const bf16x8 b = *reinterpret_cast<const bf16x8*>(&ws[0][16 * jt + m][8 * g]);
        acc[jt] = __builtin_amdgcn_mfma_f32_16x16x32_bf16(a, b, zero, 0, 0, 0);
      }
    }
#pragma unroll
    for (int kb = 1; kb < 16; ++kb) {
      const float4* p = reinterpret_cast<const float4*>(hid + (row0 + m) * H_ + 32 * kb + 8 * g);
      const bf16x8 a = pack8(p[0], p[1]);
#pragma unroll
      for (int jt = 0; jt < 4; ++jt) {
        const bf16x8 b = *reinterpret_cast<const bf16x8*>(&ws[kb][16 * jt + m][8 * g]);
        acc[jt] = __builtin_amdgcn_mfma_f32_16x16x32_bf16(a, b, acc[jt], 0, 0, 0);
      }
    }
#pragma unroll
    for (int jt = 0; jt < 4; ++jt)
#pragma unroll
      for (int r = 0; r < 4; ++r)
        out[(row0 + 4 * g + r) * NOUT_ + 16 * jt + m] = acc[jt][r];
  }
}

extern "C" void kernel_launch(void* const* d_in, const int* in_sizes, int n_in,
                              void* d_out, int out_size, void* d_ws, size_t ws_size,
                              hipStream_t stream) {
  const float* X    = (const float*)d_in[0];
  const float* h0   = (const float*)d_in[1];
  const float* W    = (const float*)d_in[2];
  const float* Win  = (const float*)d_in[3];
  const float* Wout = (const float*)d_in[4];

  float* out = (float*)d_out;                                   // [B,T,64]
  float* hid = (float*)d_out + (size_t)B_ * T_ * NOUT_;         // [B,T,512] (inp, then h)

  xproj<<<dim3(XP_BLOCKS), dim3(512), 0, stream>>>(X, Win, hid);
  rnn_scan<<<dim3(B_ / BBLK), dim3(SC_NW * 64), 0, stream>>>(h0, W, hid);
  out_proj<<<dim3(OP_BLOCKS), dim3(OP_WAVES * 64), 0, stream>>>(hid, Wout, out);
}